// Round 10
// baseline (170.712 us; speedup 1.0000x reference)
//
#include <hip/hip_runtime.h>

// DigitCaps dynamic routing, B=256 R=192 C=96 O=16 I=20. fp32 in/out.
// u_hat never materialized. R10: SEVEN dispatches:
//   prep: W->WtT bf16 k-major (coalesced-read gather); X->Xk + xT; bij=0
//   gemm1 (x3): 128m x 64n tile, split-K=15, 1-D grid 720 XCD-decoded;
//     A async global_load_lds(16B); B: it0 async, else reg-prefetch +
//     wave-local softmax scale at LDS-write; double LDS; sigma-swz;
//     partials bf16 P^T[z][n][b]
//   rsg2 (x2, it=0,1): grid 480 = 8 XCD x (12 capsules x 5 m-strips);
//     the 5 m-strip blocks of a capsule share an XCD (P region 1 L2).
//     Phase A: reduce 15z + preScale + squash -> v in PLAIN padded LDS
//     [o][b] (R10: no hand-rolled swizzle - R9's custom vB layout was
//     prime suspect for its absmax failure). Phase B: 768m x 16n GEMM
//     K=256 (24 steps, A double-buffered via proven gemm1 sigma staging,
//     issued only AFTER phase A + barrier - suspect #2 removed);
//     agreement epilogue per 128-row subtile, atomicAdd bij.
//     Within-block recompute of v -> no cross-block coherence needed.
//   redsq (x1, it=2): grid (96,4); reduce + squash -> out.
// Lessons: R1 __threadfence + R7 grid.sync = XCD coherence storm (>=100us;
//   dispatch boundary IS the cheap global barrier). R2/R3 full-K small
//   tile = 2x traffic. R4 staging chunk order must keep 4-chunks = one
//   row. R5 sigma-swz neutral-free. R6 rewrites regressed. R8 traffic
//   polish small win -> boundaries dominate. R9 unverified hand-rolled
//   LDS layout failed correctness -> replace with plainly-correct form.

#define R_ 192
#define C_ 96
#define O_ 16
#define I_ 20
#define B_ 256
#define K1 3840   // R*I
#define N_ 1536   // C*O
#define ZSPLIT 15
#define KCH 256       // K1/ZSPLIT; 4 iters of BK=64 (2x BK32 sub-tiles)
#define STILE 393216  // N_*B_ elements per z-slice

typedef unsigned short u16;
typedef __attribute__((ext_vector_type(8))) short short8;
typedef __attribute__((ext_vector_type(4))) float floatx4;

__device__ inline float bf2f(u16 h) {
  union { unsigned int u; float f; } x; x.u = ((unsigned int)h) << 16; return x.f;
}
__device__ inline u16 f2bf(float f) {
  union { float f; unsigned int u; } x; x.f = f;
  unsigned int r = x.u + 0x7FFFu + ((x.u >> 16) & 1u);
  return (u16)(r >> 16);
}
__device__ inline unsigned int pack2(float a, float b) {
  return (unsigned int)f2bf(a) | ((unsigned int)f2bf(b) << 16);
}
// async 16B/lane global->LDS; lds base wave-uniform (lane scatters +16B)
__device__ inline void async16(const u16* g, u16* l) {
  __builtin_amdgcn_global_load_lds(
      (__attribute__((address_space(1))) void*)(unsigned long long)g,
      (__attribute__((address_space(3))) void*)(unsigned int)(unsigned long long)l,
      16, 0, 0);
}

// ---- fused prep: WtT gather (5760 blocks: coalesced float4 reads of W,
// scattered 8B WtT writes -> L2-absorbed); X cast+transpose (240); bij=0
__global__ void k_prep(const float* __restrict__ W, const float* __restrict__ X,
                       u16* __restrict__ WtT, u16* __restrict__ Xk,
                       u16* __restrict__ xT, float* __restrict__ bij) {
  int bid = blockIdx.x;
  if (bid < 5760) {
    int r = bid / 30, xb = bid - r * 30;
    int j4 = (xb << 10) + ((int)threadIdx.x << 2);   // 0..30716, step 4
    // j4 = c*320 + o*20 + i; i in {0,4,8,12,16} (20=5*4: never straddles o)
    int c = j4 / 320, rem = j4 - c * 320;
    int o = rem / 20, i = rem - o * 20;
    float4 v = *(const float4*)(W + (size_t)r * (C_ * O_ * I_) + j4);
    ushort4 h;
    h.x = f2bf(v.x); h.y = f2bf(v.y); h.z = f2bf(v.z); h.w = f2bf(v.w);
    *(ushort4*)&WtT[(size_t)(c * O_ + o) * K1 + r * I_ + i] = h;
  } else if (bid < 6000) {
    __shared__ u16 tile[64][72];
    int idx = bid - 5760;
    int kb = (idx % 60) << 6, bb = (idx / 60) << 6;
    int brow = threadIdx.x >> 4;          // 0..15
    int kq = (threadIdx.x & 15) << 2;     // 0..60 step 4
    #pragma unroll
    for (int p = 0; p < 4; ++p) {
      int bl = p * 16 + brow;
      float4 v = *(const float4*)(X + (size_t)(bb + bl) * K1 + kb + kq);
      ushort4 h;
      h.x = f2bf(v.x); h.y = f2bf(v.y); h.z = f2bf(v.z); h.w = f2bf(v.w);
      *(ushort4*)(Xk + (size_t)(bb + bl) * K1 + kb + kq) = h;
      tile[kq + 0][bl] = h.x;
      tile[kq + 1][bl] = h.y;
      tile[kq + 2][bl] = h.z;
      tile[kq + 3][bl] = h.w;
    }
    __syncthreads();
    int kr = threadIdx.x >> 3;            // 0..31
    int bq = (threadIdx.x & 7) << 3;      // 0..56 step 8
    #pragma unroll
    for (int q = 0; q < 2; ++q) {
      int kl = q * 32 + kr;
      *(uint4*)(xT + (size_t)(kb + kl) * B_ + bb + bq) = *(const uint4*)&tile[kl][bq];
    }
  } else {
    int t = ((bid - 6000) * 256 + threadIdx.x) << 2;  // bij: 18,432 floats
    if (t < R_ * C_) *(float4*)&bij[t] = (float4){0.f, 0.f, 0.f, 0.f};
  }
}

// scale 8 k-contiguous bf16 (global k = kg..kg+7) by softmax row(s)
__device__ inline uint4 scale_b8(uint4 raw, int kg, const float* smrow) {
  int r0 = kg / I_;
  int bnd = (r0 + 1) * I_ - kg;                // elements j<bnd use r0
  float s0 = smrow[r0];
  float s1 = smrow[(r0 + 1 < R_) ? r0 + 1 : R_ - 1];
  union { uint4 q; u16 h[8]; } u; u.q = raw;
  #pragma unroll
  for (int j = 0; j < 8; ++j)
    u.h[j] = f2bf(bf2f(u.h[j]) * ((j < bnd) ? s0 : s1));
  return u.q;
}

// LDS sigma-swizzle layout (per buffer, per matrix):
//   elem(sub, row, q, j) -> sub*(rows*32) + row*32 + ((q+(row>>1))&3)*8 + j
// Chunk id gc = sub*(rows*4) + row*4 + sigma; staged LINEARLY at gc*16B.
// Inverse (staging source): q = (sigma - ((row>>1)&3))&3. Per 4
// consecutive chunks: one row, 4 k-groups permuted inside one 64B segment.

// ---- GEMM1: P^T[z][n][b] bf16 = (Xk[256,3840] x (c*WtT)[1536,3840]^T),
// k-chunk z. 128m x 64n tile. 1-D grid 720, XCD decode: g=bid&7,
// y=g*3+s%3, z=(s/3)%15, x=s/45.
__global__ __launch_bounds__(256) void gemm1(
    const u16* __restrict__ A, const u16* __restrict__ Bt,
    const float* __restrict__ bij, u16* __restrict__ P, int doScale) {
  __shared__ u16 As[2][8192];   // 32 KB (sigma-swz)
  __shared__ u16 Bs[2][4096];   // 16 KB (sigma-swz)
  __shared__ float sm[4][192];
  int bid = (int)blockIdx.x;
  int g = bid & 7, s5 = bid >> 3;
  int by = g * 3 + s5 % 3;
  int s3 = s5 / 3;
  int bz = s3 % 15, bx = s3 / 15;
  int tid = threadIdx.x;
  int w = tid >> 6, lane = tid & 63;
  if (doScale) {  // wave-local softmax: wave w owns capsule (by<<2)+w
    int c = (by << 2) + w;
    float e0 = bij[c * R_ + lane];
    float e1 = bij[c * R_ + lane + 64];
    float e2 = bij[c * R_ + lane + 128];
    float mx = fmaxf(e0, fmaxf(e1, e2));
    #pragma unroll
    for (int off = 32; off > 0; off >>= 1) mx = fmaxf(mx, __shfl_xor(mx, off));
    e0 = expf(e0 - mx); e1 = expf(e1 - mx); e2 = expf(e2 - mx);
    float s = e0 + e1 + e2;
    #pragma unroll
    for (int off = 32; off > 0; off >>= 1) s += __shfl_xor(s, off);
    float inv = 1.0f / s;
    sm[w][lane] = e0 * inv;
    sm[w][lane + 64] = e1 * inv;
    sm[w][lane + 128] = e2 * inv;
  }

  long m0 = (long)bx * 128, n0 = (long)by * 64;
  int k0 = bz * KCH;
  const u16* Ab = A + m0 * K1 + k0;
  const u16* Bb = Bt + n0 * K1 + k0;
  int q_s = ((lane & 3) - ((lane >> 3) & 3)) & 3;
  const u16* AgC[4]; int AlC[4];
  #pragma unroll
  for (int m = 0; m < 4; ++m) {
    AgC[m] = Ab + (long)(((m & 1) << 6) + (w << 4) + (lane >> 2)) * K1
             + ((m >> 1) << 5) + (q_s << 3);
    AlC[m] = (m << 11) + (w << 9);
  }
  const u16* BgC[2]; int BlC[2];
  #pragma unroll
  for (int m = 0; m < 2; ++m) {
    BgC[m] = Bb + (long)((w << 4) + (lane >> 2)) * K1 + (m << 5) + (q_s << 3);
    BlC[m] = (m << 11) + (w << 9);
  }
  int rowD = tid >> 2;
  int qD = ((tid & 3) - ((tid >> 3) & 3)) & 3;
  const u16* Bgs = Bb + (long)rowD * K1 + (qD << 3);
  const float* smrow = &sm[w][0];         // capsule of row rowD = rowD>>4 = w
  int wm = (w >> 1) << 6, wn = (w & 1) << 5;
  int quad = lane >> 4, lrow = lane & 15;
  int swz = ((quad + (lrow >> 1)) & 3) << 3;   // frag-read sigma slot
  floatx4 acc[4][2];
  #pragma unroll
  for (int a = 0; a < 4; ++a)
    #pragma unroll
    for (int b = 0; b < 2; ++b) acc[a][b] = (floatx4){0.f, 0.f, 0.f, 0.f};

  #pragma unroll
  for (int m = 0; m < 4; ++m) async16(AgC[m], &As[0][AlC[m]]);
  uint4 b0, b1;
  if (doScale) {
    b0 = *(const uint4*)Bgs;
    b1 = *(const uint4*)(Bgs + 32);
  } else {
    async16(BgC[0], &Bs[0][BlC[0]]);
    async16(BgC[1], &Bs[0][BlC[1]]);
  }
  __syncthreads();                   // asyncs drained; sm visible

  int p = 0;
  for (int kt = 0; kt < 4; ++kt) {
    if (doScale) {                   // thread's B k-cols: qD*8 (+32 sub1)
      int kg = k0 + (kt << 6) + (qD << 3);
      *(uint4*)&Bs[p][tid << 3] = scale_b8(b0, kg, smrow);
      *(uint4*)&Bs[p][2048 + (tid << 3)] = scale_b8(b1, kg + 32, smrow);
      __syncthreads();               // Bs[p] visible; As[p] asyncs complete
    } else if (kt > 0) {
      __syncthreads();               // buf p asyncs complete
    }
    if (kt + 1 < 4) {                // prefetch escapes the barrier drain
      int kk = (kt + 1) << 6;
      #pragma unroll
      for (int m = 0; m < 4; ++m) async16(AgC[m] + kk, &As[p ^ 1][AlC[m]]);
      if (doScale) {
        b0 = *(const uint4*)(Bgs + kk);
        b1 = *(const uint4*)(Bgs + kk + 32);
      } else {
        async16(BgC[0] + kk, &Bs[p ^ 1][BlC[0]]);
        async16(BgC[1] + kk, &Bs[p ^ 1][BlC[1]]);
      }
    }
    #pragma unroll
    for (int s = 0; s < 2; ++s) {
      short8 af[4], bfr[2];
      #pragma unroll
      for (int ms = 0; ms < 4; ++ms)
        af[ms] = *(const short8*)&As[p][(s << 12)
                                        + ((wm + ms * 16 + lrow) << 5) + swz];
      #pragma unroll
      for (int ns = 0; ns < 2; ++ns)
        bfr[ns] = *(const short8*)&Bs[p][(s << 11)
                                         + ((wn + ns * 16 + lrow) << 5) + swz];
      #pragma unroll
      for (int ms = 0; ms < 4; ++ms)
        #pragma unroll
        for (int ns = 0; ns < 2; ++ns)
          acc[ms][ns] = __builtin_amdgcn_mfma_f32_16x16x32_bf16(
              af[ms], bfr[ns], acc[ms][ns], 0, 0, 0);
    }
    p ^= 1;
  }
  size_t zb = (size_t)bz * (size_t)STILE;
  #pragma unroll
  for (int ms = 0; ms < 4; ++ms)
    #pragma unroll
    for (int ns = 0; ns < 2; ++ns) {
      int b = (int)m0 + wm + ms * 16 + (quad << 2);
      int n = (int)n0 + wn + ns * 16 + lrow;
      uint2 pk;
      pk.x = pack2(acc[ms][ns][0], acc[ms][ns][1]);
      pk.y = pack2(acc[ms][ns][2], acc[ms][ns][3]);
      *(uint2*)&P[zb + (size_t)n * B_ + b] = pk;
    }
}

// ---- fused split-K reduce + squash (it=2 only), -> out.
__global__ void k_redsq(const u16* __restrict__ P, float* __restrict__ out,
                        u16* __restrict__ vT, float preScale, int last) {
  __shared__ float nsq_l[4][64];
  int c = blockIdx.x, bh = blockIdx.y;
  int lane = threadIdx.x & 63, og = threadIdx.x >> 6;
  int b = (bh << 6) + lane;
  int n0 = (c << 4) + (og << 2);
  float acc[4];
  #pragma unroll
  for (int oo = 0; oo < 4; ++oo) acc[oo] = 0.f;
  #pragma unroll
  for (int z = 0; z < ZSPLIT; ++z) {
    size_t base = (size_t)z * STILE + (size_t)n0 * B_ + b;
    #pragma unroll
    for (int oo = 0; oo < 4; ++oo)
      acc[oo] += bf2f(P[base + (size_t)oo * B_]);
  }
  #pragma unroll
  for (int oo = 0; oo < 4; ++oo) acc[oo] *= preScale;
  float q = acc[0] * acc[0] + acc[1] * acc[1] + acc[2] * acc[2] + acc[3] * acc[3];
  nsq_l[og][lane] = q;
  __syncthreads();
  float nsq = nsq_l[0][lane] + nsq_l[1][lane] + nsq_l[2][lane] + nsq_l[3][lane];
  float f = nsq / ((1.0f + nsq) * sqrtf(nsq));
  #pragma unroll
  for (int oo = 0; oo < 4; ++oo) acc[oo] *= f;
  if (last) {
    *(float4*)(out + (size_t)b * N_ + n0) = (float4){acc[0], acc[1], acc[2], acc[3]};
  } else {
    #pragma unroll
    for (int oo = 0; oo < 4; ++oo)
      vT[(size_t)(n0 + oo) * B_ + b] = f2bf(acc[oo]);
  }
}

// ---- rsg2: fused (reduce+squash -> plain LDS v) + (768m x 16n GEMM,
// K=256) + agreement epilogue. Grid 480: g=bid&7 (XCD), s8=bid>>3,
// c = g*12 + s8%12, mstrip = s8/12 (5 m-strips of 768 k1-rows).
__global__ __launch_bounds__(256) void rsg2(
    const u16* __restrict__ P, const u16* __restrict__ A,
    const u16* __restrict__ WtT, float* __restrict__ bij, float preScale) {
  __shared__ float sv[16][258];    // s values [o][b], padded
  __shared__ float fl[256];        // squash factor per b
  __shared__ u16 vB[16][264];      // PLAIN padded v [o][b] bf16 (R10)
  __shared__ u16 As[2][8192];      // A double-buffer (gemm1 sigma scheme)
  int bid = (int)blockIdx.x;
  int g = bid & 7, s8 = bid >> 3;
  int c = g * 12 + s8 % 12;
  int mstrip = s8 / 12;                       // 0..4
  int tid = threadIdx.x;
  int w = tid >> 6, lane = tid & 63;
  int quad = lane >> 4, lrow = lane & 15;

  // ---- phase A: reduce 15 z + preScale -> sv; squash -> fl; v -> vB
  {
    int o_ = tid >> 4, bg = tid & 15;
    const u16* Pb0 = P + (size_t)((c << 4) + o_) * B_ + (bg << 3);
    float a0[8], a1[8];
    #pragma unroll
    for (int j = 0; j < 8; ++j) { a0[j] = 0.f; a1[j] = 0.f; }
    #pragma unroll
    for (int z = 0; z < ZSPLIT; ++z) {
      union { uint4 q; u16 h[8]; } u, v;
      u.q = *(const uint4*)(Pb0 + (size_t)z * STILE);
      v.q = *(const uint4*)(Pb0 + 128 + (size_t)z * STILE);
      #pragma unroll
      for (int j = 0; j < 8; ++j) { a0[j] += bf2f(u.h[j]); a1[j] += bf2f(v.h[j]); }
    }
    #pragma unroll
    for (int j = 0; j < 8; ++j) {
      sv[o_][(bg << 3) + j] = a0[j] * preScale;
      sv[o_][128 + (bg << 3) + j] = a1[j] * preScale;
    }
    __syncthreads();
    {
      int b = tid;
      float nsq = 0.f;
      #pragma unroll
      for (int o = 0; o < 16; ++o) { float v = sv[o][b]; nsq += v * v; }
      fl[b] = nsq / ((1.0f + nsq) * sqrtf(nsq));
    }
    __syncthreads();
    #pragma unroll
    for (int h = 0; h < 2; ++h) {
      int b0 = (bg << 3) + (h << 7);
      uint4 o4; unsigned int* po = (unsigned int*)&o4;
      #pragma unroll
      for (int j = 0; j < 4; ++j) {
        float lo = sv[o_][b0 + 2 * j]     * fl[b0 + 2 * j];
        float hi = sv[o_][b0 + 2 * j + 1] * fl[b0 + 2 * j + 1];
        po[j] = pack2(lo, hi);
      }
      *(uint4*)&vB[o_][b0] = o4;           // plain [o][b], 16B aligned
    }
  }
  __syncthreads();                          // vB fully visible

  // ---- A staging setup (gemm1-proven sigma scheme, K=256)
  const u16* A0 = A + (size_t)mstrip * (768 * 256);
  int q_s = ((lane & 3) - ((lane >> 3) & 3)) & 3;
  int AgP[4]; int AlC[4];
  #pragma unroll
  for (int m = 0; m < 4; ++m) {
    AgP[m] = (((m & 1) << 6) + (w << 4) + (lane >> 2)) * 256
             + ((m >> 1) << 5) + (q_s << 3);
    AlC[m] = (m << 11) + (w << 9);
  }
  #pragma unroll
  for (int m = 0; m < 4; ++m) async16(A0 + AgP[m], &As[0][AlC[m]]);  // sidx=0

  // ---- phase B: 6 m-subtiles x 4 kt, flat 24 steps, double-buffered
  int wm = w << 5;                    // wave rows within 128-row subtile
  int swzA = ((quad + (lrow >> 1)) & 3) << 3;
  floatx4 acc[2];
  acc[0] = (floatx4){0.f, 0.f, 0.f, 0.f};
  acc[1] = (floatx4){0.f, 0.f, 0.f, 0.f};
  int p = 0;
  #pragma unroll 1
  for (int sidx = 0; sidx < 24; ++sidx) {
    __syncthreads();                  // As[p] asyncs landed
    if (sidx + 1 < 24) {
      int nx = sidx + 1;
      int of = ((nx >> 2) << 15) + ((nx & 3) << 6);
      #pragma unroll
      for (int m = 0; m < 4; ++m) async16(A0 + of + AgP[m], &As[p ^ 1][AlC[m]]);
    }
    int kt = sidx & 3;
    #pragma unroll
    for (int s = 0; s < 2; ++s) {
      int ks = (kt << 1) + s;
      short8 bfr = *(const short8*)&vB[lrow][(ks << 5) + (quad << 3)];
      #pragma unroll
      for (int ms = 0; ms < 2; ++ms) {
        short8 af = *(const short8*)&As[p][(s << 12)
                       + ((wm + ms * 16 + lrow) << 5) + swzA];
        acc[ms] = __builtin_amdgcn_mfma_f32_16x16x32_bf16(af, bfr, acc[ms], 0, 0, 0);
      }
    }
    if (kt == 3) {                    // epilogue for msub = sidx>>2
      int row0 = mstrip * 768 + ((sidx >> 2) << 7);
      #pragma unroll
      for (int ms = 0; ms < 2; ++ms) {
        int rowbase = row0 + wm + ms * 16;      // wave-uniform
        int r_lo = rowbase / I_;
        int r_hi = (rowbase + 15) / I_;
        int bnd = (r_lo + 1) * I_;
        int rowl = rowbase + (quad << 2);
        int col = (c << 4) + lrow;
        uint2 wv = *(const uint2*)&WtT[(size_t)col * K1 + rowl];
        u16 hh[4];
        hh[0] = (u16)(wv.x & 0xffff); hh[1] = (u16)(wv.x >> 16);
        hh[2] = (u16)(wv.y & 0xffff); hh[3] = (u16)(wv.y >> 16);
        float p0 = 0.f, p1 = 0.f;
        #pragma unroll
        for (int e = 0; e < 4; ++e) {
          float pr = acc[ms][e] * bf2f(hh[e]);
          if (rowl + e < bnd) p0 += pr; else p1 += pr;
        }
        #pragma unroll
        for (int off = 32; off > 0; off >>= 1) {
          p0 += __shfl_xor(p0, off);
          p1 += __shfl_xor(p1, off);
        }
        if (lane == 0) {
          atomicAdd(&bij[c * R_ + r_lo], p0 * (1.0f / 256.0f));
          atomicAdd(&bij[c * R_ + r_hi], p1 * (1.0f / 256.0f));
        }
        acc[ms] = (floatx4){0.f, 0.f, 0.f, 0.f};
      }
    }
    p ^= 1;
  }
}

extern "C" void kernel_launch(void* const* d_in, const int* in_sizes, int n_in,
                              void* d_out, int out_size, void* d_ws, size_t ws_size,
                              hipStream_t stream) {
  const float* X = (const float*)d_in[0];   // fp32 [256,192,20]
  const float* W = (const float*)d_in[1];   // fp32 [192,96,16,20]
  float* out = (float*)d_out;               // fp32 [256,96,16]
  char* ws = (char*)d_ws;
  u16*  WtT = (u16*)(ws);                   // 11,796,480 B
  u16*  Xk  = (u16*)(ws + 11796480);        //  1,966,080 B
  u16*  xT  = (u16*)(ws + 13762560);        //  1,966,080 B
  u16*  vT  = (u16*)(ws + 15728640);        //    786,432 B (it=2 unused)
  u16*  Pb  = (u16*)(ws + 16515072);        // 15 z x 786,432 B = 11,796,480 B
  float* bij = (float*)(ws + 28311552);     //     73,728 B (c-major [c][r])

  k_prep<<<6018, 256, 0, stream>>>(W, X, WtT, Xk, xT, bij);

  // it=0
  gemm1<<<720, 256, 0, stream>>>(Xk, WtT, bij, Pb, 0);
  rsg2<<<480, 256, 0, stream>>>(Pb, xT, WtT, bij, 1.0f / 192.0f);
  // it=1
  gemm1<<<720, 256, 0, stream>>>(Xk, WtT, bij, Pb, 1);
  rsg2<<<480, 256, 0, stream>>>(Pb, xT, WtT, bij, 1.0f);
  // it=2
  gemm1<<<720, 256, 0, stream>>>(Xk, WtT, bij, Pb, 1);
  k_redsq<<<dim3(96, 4), 256, 0, stream>>>(Pb, out, vT, 1.0f, 1);
}

// Round 11
// 150.801 us; speedup vs baseline: 1.1320x; 1.1320x over previous
//
#include <hip/hip_runtime.h>

// DigitCaps dynamic routing, B=256 R=192 C=96 O=16 I=20. fp32 in/out.
// u_hat never materialized. 9 dispatches (R8 structure, ZSPLIT 15->12):
//   prep: W->WtT bf16 k-major (coalesced-read gather); X->Xk + xT; bij=0
//   gemm1 (x3): 128m x 64n tile, split-K=12 (kChunk 320 = 5 iters of BK64,
//     each iter = 2 BK32 sub-tiles sharing ONE barrier), 1-D grid 576
//     XCD-decoded (g=bid&7: y=g*3+s%3, z=(s/3)%12, x=s/36); A async
//     global_load_lds(16B); B: it0 async, else reg-prefetch + wave-local
//     softmax scale at LDS-write; double LDS; sigma-swz; P^T[z][n][b] bf16
//   redsq (x3): grid (96,4); 12-slice reduce (+preScale) + squash -> vT/out
//   gemm2_agree (x2): 128x64 tile, 1-D grid 720 XCD-decoded; agreement
//     epilogue vs WtT, atomicAdd bij
// Lessons: R1 __threadfence + R7 grid.sync = XCD coherence storm (>=100us;
//   dispatch boundary IS the cheap global barrier). R2/R3 full-K small
//   tile = 2x traffic. R4 staging chunk order must keep 4-chunks = one
//   row. R5 sigma-swz neutral-free. R6 rewrites regressed. R8 traffic
//   polish small win. R9 unverified LDS layout failed correctness.
//   R10 redsq+gemm2 fusion = 4x less A-reuse + 5x P reads (+23us) ->
//   within-block fusion closed on arithmetic; 9 dispatches is the floor.

#define R_ 192
#define C_ 96
#define O_ 16
#define I_ 20
#define B_ 256
#define K1 3840   // R*I
#define N_ 1536   // C*O
#define ZSPLIT 12
#define KCH 320       // K1/ZSPLIT; 5 iters of BK=64 (2x BK32 sub-tiles)
#define NKI 5         // BK64 iters per block
#define STILE 393216  // N_*B_ elements per z-slice

typedef unsigned short u16;
typedef __attribute__((ext_vector_type(8))) short short8;
typedef __attribute__((ext_vector_type(4))) float floatx4;

__device__ inline float bf2f(u16 h) {
  union { unsigned int u; float f; } x; x.u = ((unsigned int)h) << 16; return x.f;
}
__device__ inline u16 f2bf(float f) {
  union { float f; unsigned int u; } x; x.f = f;
  unsigned int r = x.u + 0x7FFFu + ((x.u >> 16) & 1u);
  return (u16)(r >> 16);
}
__device__ inline unsigned int pack2(float a, float b) {
  return (unsigned int)f2bf(a) | ((unsigned int)f2bf(b) << 16);
}
// async 16B/lane global->LDS; lds base wave-uniform (lane scatters +16B)
__device__ inline void async16(const u16* g, u16* l) {
  __builtin_amdgcn_global_load_lds(
      (__attribute__((address_space(1))) void*)(unsigned long long)g,
      (__attribute__((address_space(3))) void*)(unsigned int)(unsigned long long)l,
      16, 0, 0);
}

// ---- fused prep: WtT gather (5760 blocks: coalesced float4 reads of W,
// scattered 8B WtT writes -> L2-absorbed); X cast+transpose (240); bij=0
__global__ void k_prep(const float* __restrict__ W, const float* __restrict__ X,
                       u16* __restrict__ WtT, u16* __restrict__ Xk,
                       u16* __restrict__ xT, float* __restrict__ bij) {
  int bid = blockIdx.x;
  if (bid < 5760) {
    int r = bid / 30, xb = bid - r * 30;
    int j4 = (xb << 10) + ((int)threadIdx.x << 2);   // 0..30716, step 4
    // j4 = c*320 + o*20 + i; i in {0,4,8,12,16} (20=5*4: never straddles o)
    int c = j4 / 320, rem = j4 - c * 320;
    int o = rem / 20, i = rem - o * 20;
    float4 v = *(const float4*)(W + (size_t)r * (C_ * O_ * I_) + j4);
    ushort4 h;
    h.x = f2bf(v.x); h.y = f2bf(v.y); h.z = f2bf(v.z); h.w = f2bf(v.w);
    *(ushort4*)&WtT[(size_t)(c * O_ + o) * K1 + r * I_ + i] = h;
  } else if (bid < 6000) {
    __shared__ u16 tile[64][72];
    int idx = bid - 5760;
    int kb = (idx % 60) << 6, bb = (idx / 60) << 6;
    int brow = threadIdx.x >> 4;          // 0..15
    int kq = (threadIdx.x & 15) << 2;     // 0..60 step 4
    #pragma unroll
    for (int p = 0; p < 4; ++p) {
      int bl = p * 16 + brow;
      float4 v = *(const float4*)(X + (size_t)(bb + bl) * K1 + kb + kq);
      ushort4 h;
      h.x = f2bf(v.x); h.y = f2bf(v.y); h.z = f2bf(v.z); h.w = f2bf(v.w);
      *(ushort4*)(Xk + (size_t)(bb + bl) * K1 + kb + kq) = h;
      tile[kq + 0][bl] = h.x;
      tile[kq + 1][bl] = h.y;
      tile[kq + 2][bl] = h.z;
      tile[kq + 3][bl] = h.w;
    }
    __syncthreads();
    int kr = threadIdx.x >> 3;            // 0..31
    int bq = (threadIdx.x & 7) << 3;      // 0..56 step 8
    #pragma unroll
    for (int q = 0; q < 2; ++q) {
      int kl = q * 32 + kr;
      *(uint4*)(xT + (size_t)(kb + kl) * B_ + bb + bq) = *(const uint4*)&tile[kl][bq];
    }
  } else {
    int t = ((bid - 6000) * 256 + threadIdx.x) << 2;  // bij: 18,432 floats
    if (t < R_ * C_) *(float4*)&bij[t] = (float4){0.f, 0.f, 0.f, 0.f};
  }
}

// scale 8 k-contiguous bf16 (global k = kg..kg+7) by softmax row(s)
__device__ inline uint4 scale_b8(uint4 raw, int kg, const float* smrow) {
  int r0 = kg / I_;
  int bnd = (r0 + 1) * I_ - kg;                // elements j<bnd use r0
  float s0 = smrow[r0];
  float s1 = smrow[(r0 + 1 < R_) ? r0 + 1 : R_ - 1];
  union { uint4 q; u16 h[8]; } u; u.q = raw;
  #pragma unroll
  for (int j = 0; j < 8; ++j)
    u.h[j] = f2bf(bf2f(u.h[j]) * ((j < bnd) ? s0 : s1));
  return u.q;
}

// LDS sigma-swizzle layout (per buffer, per matrix):
//   elem(sub, row, q, j) -> sub*(rows*32) + row*32 + ((q+(row>>1))&3)*8 + j
// Chunk id gc = sub*(rows*4) + row*4 + sigma; staged LINEARLY at gc*16B.
// Inverse (staging source): q = (sigma - ((row>>1)&3))&3. Per 4
// consecutive chunks: one row, 4 k-groups permuted inside one 64B segment.

// ---- GEMM1: P^T[z][n][b] bf16 = (Xk[256,3840] x (c*WtT)[1536,3840]^T),
// k-chunk z (320 = 5 x BK64; each BK64 = 2 BK32 sub-tiles, ONE barrier).
// 128m x 64n tile. 1-D grid 576, XCD decode: g=bid&7, y=g*3+s%3,
// z=(s/3)%12, x=s/36.
__global__ __launch_bounds__(256) void gemm1(
    const u16* __restrict__ A, const u16* __restrict__ Bt,
    const float* __restrict__ bij, u16* __restrict__ P, int doScale) {
  __shared__ u16 As[2][8192];   // 32 KB (sigma-swz)
  __shared__ u16 Bs[2][4096];   // 16 KB (sigma-swz)
  __shared__ float sm[4][192];
  int bid = (int)blockIdx.x;
  int g = bid & 7, s5 = bid >> 3;
  int by = g * 3 + s5 % 3;
  int s3 = s5 / 3;
  int bz = s3 % 12, bx = s3 / 12;
  int tid = threadIdx.x;
  int w = tid >> 6, lane = tid & 63;
  if (doScale) {  // wave-local softmax: wave w owns capsule (by<<2)+w
    int c = (by << 2) + w;
    float e0 = bij[c * R_ + lane];
    float e1 = bij[c * R_ + lane + 64];
    float e2 = bij[c * R_ + lane + 128];
    float mx = fmaxf(e0, fmaxf(e1, e2));
    #pragma unroll
    for (int off = 32; off > 0; off >>= 1) mx = fmaxf(mx, __shfl_xor(mx, off));
    e0 = expf(e0 - mx); e1 = expf(e1 - mx); e2 = expf(e2 - mx);
    float s = e0 + e1 + e2;
    #pragma unroll
    for (int off = 32; off > 0; off >>= 1) s += __shfl_xor(s, off);
    float inv = 1.0f / s;
    sm[w][lane] = e0 * inv;
    sm[w][lane + 64] = e1 * inv;
    sm[w][lane + 128] = e2 * inv;
  }

  long m0 = (long)bx * 128, n0 = (long)by * 64;
  int k0 = bz * KCH;
  const u16* Ab = A + m0 * K1 + k0;
  const u16* Bb = Bt + n0 * K1 + k0;
  int q_s = ((lane & 3) - ((lane >> 3) & 3)) & 3;
  const u16* AgC[4]; int AlC[4];
  #pragma unroll
  for (int m = 0; m < 4; ++m) {
    AgC[m] = Ab + (long)(((m & 1) << 6) + (w << 4) + (lane >> 2)) * K1
             + ((m >> 1) << 5) + (q_s << 3);
    AlC[m] = (m << 11) + (w << 9);
  }
  const u16* BgC[2]; int BlC[2];
  #pragma unroll
  for (int m = 0; m < 2; ++m) {
    BgC[m] = Bb + (long)((w << 4) + (lane >> 2)) * K1 + (m << 5) + (q_s << 3);
    BlC[m] = (m << 11) + (w << 9);
  }
  int rowD = tid >> 2;
  int qD = ((tid & 3) - ((tid >> 3) & 3)) & 3;
  const u16* Bgs = Bb + (long)rowD * K1 + (qD << 3);
  const float* smrow = &sm[w][0];         // capsule of row rowD = rowD>>4 = w
  int wm = (w >> 1) << 6, wn = (w & 1) << 5;
  int quad = lane >> 4, lrow = lane & 15;
  int swz = ((quad + (lrow >> 1)) & 3) << 3;   // frag-read sigma slot
  floatx4 acc[4][2];
  #pragma unroll
  for (int a = 0; a < 4; ++a)
    #pragma unroll
    for (int b = 0; b < 2; ++b) acc[a][b] = (floatx4){0.f, 0.f, 0.f, 0.f};

  #pragma unroll
  for (int m = 0; m < 4; ++m) async16(AgC[m], &As[0][AlC[m]]);
  uint4 b0, b1;
  if (doScale) {
    b0 = *(const uint4*)Bgs;
    b1 = *(const uint4*)(Bgs + 32);
  } else {
    async16(BgC[0], &Bs[0][BlC[0]]);
    async16(BgC[1], &Bs[0][BlC[1]]);
  }
  __syncthreads();                   // asyncs drained; sm visible

  int p = 0;
  for (int kt = 0; kt < NKI; ++kt) {
    if (doScale) {                   // thread's B k-cols: qD*8 (+32 sub1)
      int kg = k0 + (kt << 6) + (qD << 3);
      *(uint4*)&Bs[p][tid << 3] = scale_b8(b0, kg, smrow);
      *(uint4*)&Bs[p][2048 + (tid << 3)] = scale_b8(b1, kg + 32, smrow);
      __syncthreads();               // Bs[p] visible; As[p] asyncs complete
    } else if (kt > 0) {
      __syncthreads();               // buf p asyncs complete
    }
    if (kt + 1 < NKI) {              // prefetch escapes the barrier drain
      int kk = (kt + 1) << 6;
      #pragma unroll
      for (int m = 0; m < 4; ++m) async16(AgC[m] + kk, &As[p ^ 1][AlC[m]]);
      if (doScale) {
        b0 = *(const uint4*)(Bgs + kk);
        b1 = *(const uint4*)(Bgs + kk + 32);
      } else {
        async16(BgC[0] + kk, &Bs[p ^ 1][BlC[0]]);
        async16(BgC[1] + kk, &Bs[p ^ 1][BlC[1]]);
      }
    }
    #pragma unroll
    for (int s = 0; s < 2; ++s) {
      short8 af[4], bfr[2];
      #pragma unroll
      for (int ms = 0; ms < 4; ++ms)
        af[ms] = *(const short8*)&As[p][(s << 12)
                                        + ((wm + ms * 16 + lrow) << 5) + swz];
      #pragma unroll
      for (int ns = 0; ns < 2; ++ns)
        bfr[ns] = *(const short8*)&Bs[p][(s << 11)
                                         + ((wn + ns * 16 + lrow) << 5) + swz];
      #pragma unroll
      for (int ms = 0; ms < 4; ++ms)
        #pragma unroll
        for (int ns = 0; ns < 2; ++ns)
          acc[ms][ns] = __builtin_amdgcn_mfma_f32_16x16x32_bf16(
              af[ms], bfr[ns], acc[ms][ns], 0, 0, 0);
    }
    p ^= 1;
  }
  size_t zb = (size_t)bz * (size_t)STILE;
  #pragma unroll
  for (int ms = 0; ms < 4; ++ms)
    #pragma unroll
    for (int ns = 0; ns < 2; ++ns) {
      int b = (int)m0 + wm + ms * 16 + (quad << 2);
      int n = (int)n0 + wn + ns * 16 + lrow;
      uint2 pk;
      pk.x = pack2(acc[ms][ns][0], acc[ms][ns][1]);
      pk.y = pack2(acc[ms][ns][2], acc[ms][ns][3]);
      *(uint2*)&P[zb + (size_t)n * B_ + b] = pk;
    }
}

// ---- fused split-K reduce + squash, reading P^T[z][n][b] bf16.
// grid (96 c, 4 b-quarters); block 256 = 4 o-groups x 64 lanes; 1 b/lane.
__global__ void k_redsq(const u16* __restrict__ P, float* __restrict__ out,
                        u16* __restrict__ vT, float preScale, int last) {
  __shared__ float nsq_l[4][64];
  int c = blockIdx.x, bh = blockIdx.y;
  int lane = threadIdx.x & 63, og = threadIdx.x >> 6;
  int b = (bh << 6) + lane;
  int n0 = (c << 4) + (og << 2);
  float acc[4];
  #pragma unroll
  for (int oo = 0; oo < 4; ++oo) acc[oo] = 0.f;
  #pragma unroll
  for (int z = 0; z < ZSPLIT; ++z) {
    size_t base = (size_t)z * STILE + (size_t)n0 * B_ + b;
    #pragma unroll
    for (int oo = 0; oo < 4; ++oo)
      acc[oo] += bf2f(P[base + (size_t)oo * B_]);
  }
  #pragma unroll
  for (int oo = 0; oo < 4; ++oo) acc[oo] *= preScale;
  float q = acc[0] * acc[0] + acc[1] * acc[1] + acc[2] * acc[2] + acc[3] * acc[3];
  nsq_l[og][lane] = q;
  __syncthreads();
  float nsq = nsq_l[0][lane] + nsq_l[1][lane] + nsq_l[2][lane] + nsq_l[3][lane];
  float f = nsq / ((1.0f + nsq) * sqrtf(nsq));
  #pragma unroll
  for (int oo = 0; oo < 4; ++oo) acc[oo] *= f;
  if (last) {
    *(float4*)(out + (size_t)b * N_ + n0) = (float4){acc[0], acc[1], acc[2], acc[3]};
  } else {
    #pragma unroll
    for (int oo = 0; oo < 4; ++oo)
      vT[(size_t)(n0 + oo) * B_ + b] = f2bf(acc[oo]);
  }
}

// ---- GEMM2 + agreement fused, 128m x 64n tile, K=256 = 4 x BK64
// (2 BK32 sub-tiles per barrier), fully async staging; sigma-swz.
// 1-D grid 720, XCD decode: y=g*3+s%3, x=s/3 -> vT B-tiles single-L2.
__global__ __launch_bounds__(256) void gemm2_agree(
    const u16* __restrict__ A, const u16* __restrict__ Bt,
    const u16* __restrict__ WtT, float* __restrict__ bij) {
  const int K = 256;
  __shared__ u16 As[2][8192];
  __shared__ u16 Bs[2][4096];
  int bid = (int)blockIdx.x;
  int g = bid & 7, s5 = bid >> 3;
  int by = g * 3 + s5 % 3;
  int bx = s5 / 3;                   // 0..29
  int tid = threadIdx.x;
  long m0 = (long)bx * 128, n0 = (long)by * 64;
  const u16* Ab = A + m0 * K;
  const u16* Bb = Bt + n0 * K;
  int w = tid >> 6, lane = tid & 63;
  int wm = (w >> 1) << 6, wn = (w & 1) << 5;
  int quad = lane >> 4, lrow = lane & 15;
  int swz = ((quad + (lrow >> 1)) & 3) << 3;
  int q_s = ((lane & 3) - ((lane >> 3) & 3)) & 3;
  const u16* AgC[4]; int AlC[4];
  #pragma unroll
  for (int m = 0; m < 4; ++m) {
    AgC[m] = Ab + (long)(((m & 1) << 6) + (w << 4) + (lane >> 2)) * K
             + ((m >> 1) << 5) + (q_s << 3);
    AlC[m] = (m << 11) + (w << 9);
  }
  const u16* BgC[2]; int BlC[2];
  #pragma unroll
  for (int m = 0; m < 2; ++m) {
    BgC[m] = Bb + (long)((w << 4) + (lane >> 2)) * K + (m << 5) + (q_s << 3);
    BlC[m] = (m << 11) + (w << 9);
  }
  floatx4 acc[4][2];
  #pragma unroll
  for (int a = 0; a < 4; ++a)
    #pragma unroll
    for (int b = 0; b < 2; ++b) acc[a][b] = (floatx4){0.f, 0.f, 0.f, 0.f};

  #pragma unroll
  for (int m = 0; m < 4; ++m) async16(AgC[m], &As[0][AlC[m]]);
  async16(BgC[0], &Bs[0][BlC[0]]);
  async16(BgC[1], &Bs[0][BlC[1]]);

  int p = 0;
  #pragma unroll
  for (int kt = 0; kt < 4; ++kt) {
    __syncthreads();                 // buf p asyncs complete
    if (kt + 1 < 4) {                // async prefetch escapes the drain
      int kk = (kt + 1) << 6;
      #pragma unroll
      for (int m = 0; m < 4; ++m) async16(AgC[m] + kk, &As[p ^ 1][AlC[m]]);
      async16(BgC[0] + kk, &Bs[p ^ 1][BlC[0]]);
      async16(BgC[1] + kk, &Bs[p ^ 1][BlC[1]]);
    }
    #pragma unroll
    for (int s = 0; s < 2; ++s) {
      short8 af[4], bfr[2];
      #pragma unroll
      for (int ms = 0; ms < 4; ++ms)
        af[ms] = *(const short8*)&As[p][(s << 12)
                                        + ((wm + ms * 16 + lrow) << 5) + swz];
      #pragma unroll
      for (int ns = 0; ns < 2; ++ns)
        bfr[ns] = *(const short8*)&Bs[p][(s << 11)
                                         + ((wn + ns * 16 + lrow) << 5) + swz];
      #pragma unroll
      for (int ms = 0; ms < 4; ++ms)
        #pragma unroll
        for (int ns = 0; ns < 2; ++ns)
          acc[ms][ns] = __builtin_amdgcn_mfma_f32_16x16x32_bf16(
              af[ms], bfr[ns], acc[ms][ns], 0, 0, 0);
    }
    p ^= 1;
  }
  // epilogue: per fragment, cols = one capsule c; 16 rows span <=2 routes r.
  #pragma unroll
  for (int ms = 0; ms < 4; ++ms) {
    int rowbase = (int)m0 + wm + ms * 16;          // wave-uniform
    int r_lo = rowbase / I_;
    int r_hi = (rowbase + 15) / I_;
    int bnd = (r_lo + 1) * I_;
    int rowl = rowbase + (quad << 2);
    #pragma unroll
    for (int ns = 0; ns < 2; ++ns) {
      int col = (int)n0 + wn + ns * 16 + lrow;
      uint2 wv = *(const uint2*)&WtT[(size_t)col * K1 + rowl];
      u16 h[4];
      h[0] = (u16)(wv.x & 0xffff); h[1] = (u16)(wv.x >> 16);
      h[2] = (u16)(wv.y & 0xffff); h[3] = (u16)(wv.y >> 16);
      float p0 = 0.f, p1 = 0.f;
      #pragma unroll
      for (int e = 0; e < 4; ++e) {
        float pr = acc[ms][ns][e] * bf2f(h[e]);
        if (rowl + e < bnd) p0 += pr; else p1 += pr;
      }
      #pragma unroll
      for (int off = 32; off > 0; off >>= 1) {
        p0 += __shfl_xor(p0, off);
        p1 += __shfl_xor(p1, off);
      }
      if (lane == 0) {
        int c = col >> 4;
        atomicAdd(&bij[c * R_ + r_lo], p0 * (1.0f / 256.0f));
        atomicAdd(&bij[c * R_ + r_hi], p1 * (1.0f / 256.0f));
      }
    }
  }
}

extern "C" void kernel_launch(void* const* d_in, const int* in_sizes, int n_in,
                              void* d_out, int out_size, void* d_ws, size_t ws_size,
                              hipStream_t stream) {
  const float* X = (const float*)d_in[0];   // fp32 [256,192,20]
  const float* W = (const float*)d_in[1];   // fp32 [192,96,16,20]
  float* out = (float*)d_out;               // fp32 [256,96,16]
  char* ws = (char*)d_ws;
  u16*  WtT = (u16*)(ws);                   // 11,796,480 B
  u16*  Xk  = (u16*)(ws + 11796480);        //  1,966,080 B
  u16*  xT  = (u16*)(ws + 13762560);        //  1,966,080 B
  u16*  vT  = (u16*)(ws + 15728640);        //    786,432 B
  u16*  Pb  = (u16*)(ws + 16515072);        // 12 z x 786,432 B = 9,437,184 B
  float* bij = (float*)(ws + 28311552);     //     73,728 B (c-major [c][r])

  k_prep<<<6018, 256, 0, stream>>>(W, X, WtT, Xk, xT, bij);

  for (int it = 0; it < 3; ++it) {
    // s partials: M=256,N=1536,K=3840, grid 576 (XCD-decoded), 5 BK64 iters.
    // iter 0: no scale in gemm1; uniform softmax 1/192 applied in redsq.
    gemm1<<<576, 256, 0, stream>>>(Xk, WtT, bij, Pb, it > 0);
    k_redsq<<<dim3(96, 4), 256, 0, stream>>>(
        Pb, out, vT, it == 0 ? (1.0f / 192.0f) : 1.0f, it == 2);
    if (it < 2)
      gemm2_agree<<<720, 256, 0, stream>>>(xT, vT, WtT, bij);
  }
}

// Round 12
// 147.609 us; speedup vs baseline: 1.1565x; 1.0216x over previous
//
#include <hip/hip_runtime.h>

// DigitCaps dynamic routing, B=256 R=192 C=96 O=16 I=20. fp32 in/out.
// u_hat never materialized. 9 dispatches (R8 = measured best, 147.4us).
//   prep: W->WtT bf16 k-major (coalesced-read gather, scattered 8B writes
//     L2-absorbed); X->Xk + xT; bij=0 (c-major)
//   gemm1 (x3): 128m x 64n tile, split-K=15 (kChunk 256 = 4 iters of BK64,
//     each iter = 2 BK32 sub-tiles sharing ONE barrier), 1-D grid 720
//     XCD-decoded (g=bid&7: y=g*3+s%3, z=(s/3)%15, x=s/45); A async
//     global_load_lds(16B); B: it0 async, else reg-prefetch + wave-local
//     softmax scale at LDS-write; double LDS; sigma-swz; P^T[z][n][b] bf16
//   redsq (x3): grid (96,4); split-K reduce (+preScale) + squash -> vT/out
//   gemm2_agree (x2): 128x64 tile, 1-D grid 720 XCD-decoded; agreement
//     epilogue vs WtT, atomicAdd bij
// STRUCTURAL FLOOR (12-round evidence): kernel work ~40us + 8 dispatch
// boundaries x ~13us = ~147us. Boundaries irreducible: any in-kernel
// global coherence on 8-XCD MI355X costs >=100us (R1 fence storm 459us,
// R7 grid.sync 897us); within-block fusion trades >=4x operand reuse
// (R10 +23us); full-K doubles traffic (R2/R3). In-kernel polish null
// because boundaries are 75% of runtime (R5/R6/R8/R11 all within +-2%).

#define R_ 192
#define C_ 96
#define O_ 16
#define I_ 20
#define B_ 256
#define K1 3840   // R*I
#define N_ 1536   // C*O
#define ZSPLIT 15
#define KCH 256       // K1/ZSPLIT; 4 iters of BK=64 (2x BK32 sub-tiles)
#define STILE 393216  // N_*B_ elements per z-slice

typedef unsigned short u16;
typedef __attribute__((ext_vector_type(8))) short short8;
typedef __attribute__((ext_vector_type(4))) float floatx4;

__device__ inline float bf2f(u16 h) {
  union { unsigned int u; float f; } x; x.u = ((unsigned int)h) << 16; return x.f;
}
__device__ inline u16 f2bf(float f) {
  union { float f; unsigned int u; } x; x.f = f;
  unsigned int r = x.u + 0x7FFFu + ((x.u >> 16) & 1u);
  return (u16)(r >> 16);
}
__device__ inline unsigned int pack2(float a, float b) {
  return (unsigned int)f2bf(a) | ((unsigned int)f2bf(b) << 16);
}
// async 16B/lane global->LDS; lds base wave-uniform (lane scatters +16B)
__device__ inline void async16(const u16* g, u16* l) {
  __builtin_amdgcn_global_load_lds(
      (__attribute__((address_space(1))) void*)(unsigned long long)g,
      (__attribute__((address_space(3))) void*)(unsigned int)(unsigned long long)l,
      16, 0, 0);
}

// ---- fused prep: WtT gather (5760 blocks: coalesced float4 reads of W,
// scattered 8B WtT writes -> L2-absorbed); X cast+transpose (240); bij=0
__global__ void k_prep(const float* __restrict__ W, const float* __restrict__ X,
                       u16* __restrict__ WtT, u16* __restrict__ Xk,
                       u16* __restrict__ xT, float* __restrict__ bij) {
  int bid = blockIdx.x;
  if (bid < 5760) {
    int r = bid / 30, xb = bid - r * 30;
    int j4 = (xb << 10) + ((int)threadIdx.x << 2);   // 0..30716, step 4
    // j4 = c*320 + o*20 + i; i in {0,4,8,12,16} (20=5*4: never straddles o)
    int c = j4 / 320, rem = j4 - c * 320;
    int o = rem / 20, i = rem - o * 20;
    float4 v = *(const float4*)(W + (size_t)r * (C_ * O_ * I_) + j4);
    ushort4 h;
    h.x = f2bf(v.x); h.y = f2bf(v.y); h.z = f2bf(v.z); h.w = f2bf(v.w);
    *(ushort4*)&WtT[(size_t)(c * O_ + o) * K1 + r * I_ + i] = h;
  } else if (bid < 6000) {
    __shared__ u16 tile[64][72];
    int idx = bid - 5760;
    int kb = (idx % 60) << 6, bb = (idx / 60) << 6;
    int brow = threadIdx.x >> 4;          // 0..15
    int kq = (threadIdx.x & 15) << 2;     // 0..60 step 4
    #pragma unroll
    for (int p = 0; p < 4; ++p) {
      int bl = p * 16 + brow;
      float4 v = *(const float4*)(X + (size_t)(bb + bl) * K1 + kb + kq);
      ushort4 h;
      h.x = f2bf(v.x); h.y = f2bf(v.y); h.z = f2bf(v.z); h.w = f2bf(v.w);
      *(ushort4*)(Xk + (size_t)(bb + bl) * K1 + kb + kq) = h;
      tile[kq + 0][bl] = h.x;
      tile[kq + 1][bl] = h.y;
      tile[kq + 2][bl] = h.z;
      tile[kq + 3][bl] = h.w;
    }
    __syncthreads();
    int kr = threadIdx.x >> 3;            // 0..31
    int bq = (threadIdx.x & 7) << 3;      // 0..56 step 8
    #pragma unroll
    for (int q = 0; q < 2; ++q) {
      int kl = q * 32 + kr;
      *(uint4*)(xT + (size_t)(kb + kl) * B_ + bb + bq) = *(const uint4*)&tile[kl][bq];
    }
  } else {
    int t = ((bid - 6000) * 256 + threadIdx.x) << 2;  // bij: 18,432 floats
    if (t < R_ * C_) *(float4*)&bij[t] = (float4){0.f, 0.f, 0.f, 0.f};
  }
}

// scale 8 k-contiguous bf16 (global k = kg..kg+7) by softmax row(s)
__device__ inline uint4 scale_b8(uint4 raw, int kg, const float* smrow) {
  int r0 = kg / I_;
  int bnd = (r0 + 1) * I_ - kg;                // elements j<bnd use r0
  float s0 = smrow[r0];
  float s1 = smrow[(r0 + 1 < R_) ? r0 + 1 : R_ - 1];
  union { uint4 q; u16 h[8]; } u; u.q = raw;
  #pragma unroll
  for (int j = 0; j < 8; ++j)
    u.h[j] = f2bf(bf2f(u.h[j]) * ((j < bnd) ? s0 : s1));
  return u.q;
}

// LDS sigma-swizzle layout (per buffer, per matrix):
//   elem(sub, row, q, j) -> sub*(rows*32) + row*32 + ((q+(row>>1))&3)*8 + j
// Chunk id gc = sub*(rows*4) + row*4 + sigma; staged LINEARLY at gc*16B.
// Inverse (staging source): q = (sigma - ((row>>1)&3))&3. Per 4
// consecutive chunks: one row, 4 k-groups permuted inside one 64B segment.

// ---- GEMM1: P^T[z][n][b] bf16 = (Xk[256,3840] x (c*WtT)[1536,3840]^T),
// k-chunk z (256 = 4 x BK64; each BK64 = 2 BK32 sub-tiles, ONE barrier).
// 128m x 64n tile. 1-D grid 720, XCD decode: g=bid&7, y=g*3+s%3,
// z=(s/3)%15, x=s/45.
__global__ __launch_bounds__(256) void gemm1(
    const u16* __restrict__ A, const u16* __restrict__ Bt,
    const float* __restrict__ bij, u16* __restrict__ P, int doScale) {
  __shared__ u16 As[2][8192];   // 32 KB (sigma-swz)
  __shared__ u16 Bs[2][4096];   // 16 KB (sigma-swz)
  __shared__ float sm[4][192];
  int bid = (int)blockIdx.x;
  int g = bid & 7, s5 = bid >> 3;
  int by = g * 3 + s5 % 3;
  int s3 = s5 / 3;
  int bz = s3 % 15, bx = s3 / 15;
  int tid = threadIdx.x;
  int w = tid >> 6, lane = tid & 63;
  if (doScale) {  // wave-local softmax: wave w owns capsule (by<<2)+w
    int c = (by << 2) + w;
    float e0 = bij[c * R_ + lane];
    float e1 = bij[c * R_ + lane + 64];
    float e2 = bij[c * R_ + lane + 128];
    float mx = fmaxf(e0, fmaxf(e1, e2));
    #pragma unroll
    for (int off = 32; off > 0; off >>= 1) mx = fmaxf(mx, __shfl_xor(mx, off));
    e0 = expf(e0 - mx); e1 = expf(e1 - mx); e2 = expf(e2 - mx);
    float s = e0 + e1 + e2;
    #pragma unroll
    for (int off = 32; off > 0; off >>= 1) s += __shfl_xor(s, off);
    float inv = 1.0f / s;
    sm[w][lane] = e0 * inv;
    sm[w][lane + 64] = e1 * inv;
    sm[w][lane + 128] = e2 * inv;
  }

  long m0 = (long)bx * 128, n0 = (long)by * 64;
  int k0 = bz * KCH;
  const u16* Ab = A + m0 * K1 + k0;
  const u16* Bb = Bt + n0 * K1 + k0;
  int q_s = ((lane & 3) - ((lane >> 3) & 3)) & 3;
  const u16* AgC[4]; int AlC[4];
  #pragma unroll
  for (int m = 0; m < 4; ++m) {
    AgC[m] = Ab + (long)(((m & 1) << 6) + (w << 4) + (lane >> 2)) * K1
             + ((m >> 1) << 5) + (q_s << 3);
    AlC[m] = (m << 11) + (w << 9);
  }
  const u16* BgC[2]; int BlC[2];
  #pragma unroll
  for (int m = 0; m < 2; ++m) {
    BgC[m] = Bb + (long)((w << 4) + (lane >> 2)) * K1 + (m << 5) + (q_s << 3);
    BlC[m] = (m << 11) + (w << 9);
  }
  int rowD = tid >> 2;
  int qD = ((tid & 3) - ((tid >> 3) & 3)) & 3;
  const u16* Bgs = Bb + (long)rowD * K1 + (qD << 3);
  const float* smrow = &sm[w][0];         // capsule of row rowD = rowD>>4 = w
  int wm = (w >> 1) << 6, wn = (w & 1) << 5;
  int quad = lane >> 4, lrow = lane & 15;
  int swz = ((quad + (lrow >> 1)) & 3) << 3;   // frag-read sigma slot
  floatx4 acc[4][2];
  #pragma unroll
  for (int a = 0; a < 4; ++a)
    #pragma unroll
    for (int b = 0; b < 2; ++b) acc[a][b] = (floatx4){0.f, 0.f, 0.f, 0.f};

  #pragma unroll
  for (int m = 0; m < 4; ++m) async16(AgC[m], &As[0][AlC[m]]);
  uint4 b0, b1;
  if (doScale) {
    b0 = *(const uint4*)Bgs;
    b1 = *(const uint4*)(Bgs + 32);
  } else {
    async16(BgC[0], &Bs[0][BlC[0]]);
    async16(BgC[1], &Bs[0][BlC[1]]);
  }
  __syncthreads();                   // asyncs drained; sm visible

  int p = 0;
  for (int kt = 0; kt < 4; ++kt) {
    if (doScale) {                   // thread's B k-cols: qD*8 (+32 sub1)
      int kg = k0 + (kt << 6) + (qD << 3);
      *(uint4*)&Bs[p][tid << 3] = scale_b8(b0, kg, smrow);
      *(uint4*)&Bs[p][2048 + (tid << 3)] = scale_b8(b1, kg + 32, smrow);
      __syncthreads();               // Bs[p] visible; As[p] asyncs complete
    } else if (kt > 0) {
      __syncthreads();               // buf p asyncs complete
    }
    if (kt + 1 < 4) {                // prefetch escapes the barrier drain
      int kk = (kt + 1) << 6;
      #pragma unroll
      for (int m = 0; m < 4; ++m) async16(AgC[m] + kk, &As[p ^ 1][AlC[m]]);
      if (doScale) {
        b0 = *(const uint4*)(Bgs + kk);
        b1 = *(const uint4*)(Bgs + kk + 32);
      } else {
        async16(BgC[0] + kk, &Bs[p ^ 1][BlC[0]]);
        async16(BgC[1] + kk, &Bs[p ^ 1][BlC[1]]);
      }
    }
    #pragma unroll
    for (int s = 0; s < 2; ++s) {
      short8 af[4], bfr[2];
      #pragma unroll
      for (int ms = 0; ms < 4; ++ms)
        af[ms] = *(const short8*)&As[p][(s << 12)
                                        + ((wm + ms * 16 + lrow) << 5) + swz];
      #pragma unroll
      for (int ns = 0; ns < 2; ++ns)
        bfr[ns] = *(const short8*)&Bs[p][(s << 11)
                                         + ((wn + ns * 16 + lrow) << 5) + swz];
      #pragma unroll
      for (int ms = 0; ms < 4; ++ms)
        #pragma unroll
        for (int ns = 0; ns < 2; ++ns)
          acc[ms][ns] = __builtin_amdgcn_mfma_f32_16x16x32_bf16(
              af[ms], bfr[ns], acc[ms][ns], 0, 0, 0);
    }
    p ^= 1;
  }
  size_t zb = (size_t)bz * (size_t)STILE;
  #pragma unroll
  for (int ms = 0; ms < 4; ++ms)
    #pragma unroll
    for (int ns = 0; ns < 2; ++ns) {
      int b = (int)m0 + wm + ms * 16 + (quad << 2);
      int n = (int)n0 + wn + ns * 16 + lrow;
      uint2 pk;
      pk.x = pack2(acc[ms][ns][0], acc[ms][ns][1]);
      pk.y = pack2(acc[ms][ns][2], acc[ms][ns][3]);
      *(uint2*)&P[zb + (size_t)n * B_ + b] = pk;
    }
}

// ---- fused split-K reduce + squash, reading P^T[z][n][b] bf16.
// grid (96 c, 4 b-quarters); block 256 = 4 o-groups x 64 lanes; 1 b/lane.
__global__ void k_redsq(const u16* __restrict__ P, float* __restrict__ out,
                        u16* __restrict__ vT, float preScale, int last) {
  __shared__ float nsq_l[4][64];
  int c = blockIdx.x, bh = blockIdx.y;
  int lane = threadIdx.x & 63, og = threadIdx.x >> 6;
  int b = (bh << 6) + lane;
  int n0 = (c << 4) + (og << 2);
  float acc[4];
  #pragma unroll
  for (int oo = 0; oo < 4; ++oo) acc[oo] = 0.f;
  #pragma unroll
  for (int z = 0; z < ZSPLIT; ++z) {
    size_t base = (size_t)z * STILE + (size_t)n0 * B_ + b;
    #pragma unroll
    for (int oo = 0; oo < 4; ++oo)
      acc[oo] += bf2f(P[base + (size_t)oo * B_]);
  }
  #pragma unroll
  for (int oo = 0; oo < 4; ++oo) acc[oo] *= preScale;
  float q = acc[0] * acc[0] + acc[1] * acc[1] + acc[2] * acc[2] + acc[3] * acc[3];
  nsq_l[og][lane] = q;
  __syncthreads();
  float nsq = nsq_l[0][lane] + nsq_l[1][lane] + nsq_l[2][lane] + nsq_l[3][lane];
  float f = nsq / ((1.0f + nsq) * sqrtf(nsq));
  #pragma unroll
  for (int oo = 0; oo < 4; ++oo) acc[oo] *= f;
  if (last) {
    *(float4*)(out + (size_t)b * N_ + n0) = (float4){acc[0], acc[1], acc[2], acc[3]};
  } else {
    #pragma unroll
    for (int oo = 0; oo < 4; ++oo)
      vT[(size_t)(n0 + oo) * B_ + b] = f2bf(acc[oo]);
  }
}

// ---- GEMM2 + agreement fused, 128m x 64n tile, K=256 = 4 x BK64
// (2 BK32 sub-tiles per barrier), fully async staging; sigma-swz.
// 1-D grid 720, XCD decode: y=g*3+s%3, x=s/3 -> vT B-tiles single-L2.
__global__ __launch_bounds__(256) void gemm2_agree(
    const u16* __restrict__ A, const u16* __restrict__ Bt,
    const u16* __restrict__ WtT, float* __restrict__ bij) {
  const int K = 256;
  __shared__ u16 As[2][8192];
  __shared__ u16 Bs[2][4096];
  int bid = (int)blockIdx.x;
  int g = bid & 7, s5 = bid >> 3;
  int by = g * 3 + s5 % 3;
  int bx = s5 / 3;                   // 0..29
  int tid = threadIdx.x;
  long m0 = (long)bx * 128, n0 = (long)by * 64;
  const u16* Ab = A + m0 * K;
  const u16* Bb = Bt + n0 * K;
  int w = tid >> 6, lane = tid & 63;
  int wm = (w >> 1) << 6, wn = (w & 1) << 5;
  int quad = lane >> 4, lrow = lane & 15;
  int swz = ((quad + (lrow >> 1)) & 3) << 3;
  int q_s = ((lane & 3) - ((lane >> 3) & 3)) & 3;
  const u16* AgC[4]; int AlC[4];
  #pragma unroll
  for (int m = 0; m < 4; ++m) {
    AgC[m] = Ab + (long)(((m & 1) << 6) + (w << 4) + (lane >> 2)) * K
             + ((m >> 1) << 5) + (q_s << 3);
    AlC[m] = (m << 11) + (w << 9);
  }
  const u16* BgC[2]; int BlC[2];
  #pragma unroll
  for (int m = 0; m < 2; ++m) {
    BgC[m] = Bb + (long)((w << 4) + (lane >> 2)) * K + (m << 5) + (q_s << 3);
    BlC[m] = (m << 11) + (w << 9);
  }
  floatx4 acc[4][2];
  #pragma unroll
  for (int a = 0; a < 4; ++a)
    #pragma unroll
    for (int b = 0; b < 2; ++b) acc[a][b] = (floatx4){0.f, 0.f, 0.f, 0.f};

  #pragma unroll
  for (int m = 0; m < 4; ++m) async16(AgC[m], &As[0][AlC[m]]);
  async16(BgC[0], &Bs[0][BlC[0]]);
  async16(BgC[1], &Bs[0][BlC[1]]);

  int p = 0;
  #pragma unroll
  for (int kt = 0; kt < 4; ++kt) {
    __syncthreads();                 // buf p asyncs complete
    if (kt + 1 < 4) {                // async prefetch escapes the drain
      int kk = (kt + 1) << 6;
      #pragma unroll
      for (int m = 0; m < 4; ++m) async16(AgC[m] + kk, &As[p ^ 1][AlC[m]]);
      async16(BgC[0] + kk, &Bs[p ^ 1][BlC[0]]);
      async16(BgC[1] + kk, &Bs[p ^ 1][BlC[1]]);
    }
    #pragma unroll
    for (int s = 0; s < 2; ++s) {
      short8 af[4], bfr[2];
      #pragma unroll
      for (int ms = 0; ms < 4; ++ms)
        af[ms] = *(const short8*)&As[p][(s << 12)
                                        + ((wm + ms * 16 + lrow) << 5) + swz];
      #pragma unroll
      for (int ns = 0; ns < 2; ++ns)
        bfr[ns] = *(const short8*)&Bs[p][(s << 11)
                                         + ((wn + ns * 16 + lrow) << 5) + swz];
      #pragma unroll
      for (int ms = 0; ms < 4; ++ms)
        #pragma unroll
        for (int ns = 0; ns < 2; ++ns)
          acc[ms][ns] = __builtin_amdgcn_mfma_f32_16x16x32_bf16(
              af[ms], bfr[ns], acc[ms][ns], 0, 0, 0);
    }
    p ^= 1;
  }
  // epilogue: per fragment, cols = one capsule c; 16 rows span <=2 routes r.
  #pragma unroll
  for (int ms = 0; ms < 4; ++ms) {
    int rowbase = (int)m0 + wm + ms * 16;          // wave-uniform
    int r_lo = rowbase / I_;
    int r_hi = (rowbase + 15) / I_;
    int bnd = (r_lo + 1) * I_;
    int rowl = rowbase + (quad << 2);
    #pragma unroll
    for (int ns = 0; ns < 2; ++ns) {
      int col = (int)n0 + wn + ns * 16 + lrow;
      uint2 wv = *(const uint2*)&WtT[(size_t)col * K1 + rowl];
      u16 h[4];
      h[0] = (u16)(wv.x & 0xffff); h[1] = (u16)(wv.x >> 16);
      h[2] = (u16)(wv.y & 0xffff); h[3] = (u16)(wv.y >> 16);
      float p0 = 0.f, p1 = 0.f;
      #pragma unroll
      for (int e = 0; e < 4; ++e) {
        float pr = acc[ms][ns][e] * bf2f(h[e]);
        if (rowl + e < bnd) p0 += pr; else p1 += pr;
      }
      #pragma unroll
      for (int off = 32; off > 0; off >>= 1) {
        p0 += __shfl_xor(p0, off);
        p1 += __shfl_xor(p1, off);
      }
      if (lane == 0) {
        int c = col >> 4;
        atomicAdd(&bij[c * R_ + r_lo], p0 * (1.0f / 256.0f));
        atomicAdd(&bij[c * R_ + r_hi], p1 * (1.0f / 256.0f));
      }
    }
  }
}

extern "C" void kernel_launch(void* const* d_in, const int* in_sizes, int n_in,
                              void* d_out, int out_size, void* d_ws, size_t ws_size,
                              hipStream_t stream) {
  const float* X = (const float*)d_in[0];   // fp32 [256,192,20]
  const float* W = (const float*)d_in[1];   // fp32 [192,96,16,20]
  float* out = (float*)d_out;               // fp32 [256,96,16]
  char* ws = (char*)d_ws;
  u16*  WtT = (u16*)(ws);                   // 11,796,480 B
  u16*  Xk  = (u16*)(ws + 11796480);        //  1,966,080 B
  u16*  xT  = (u16*)(ws + 13762560);        //  1,966,080 B
  u16*  vT  = (u16*)(ws + 15728640);        //    786,432 B
  u16*  Pb  = (u16*)(ws + 16515072);        // 15 z x 786,432 B = 11,796,480 B
  float* bij = (float*)(ws + 28311552);     //     73,728 B (c-major [c][r])

  k_prep<<<6018, 256, 0, stream>>>(W, X, WtT, Xk, xT, bij);

  for (int it = 0; it < 3; ++it) {
    // s partials: M=256,N=1536,K=3840, grid 720 (XCD-decoded), 4 BK64 iters.
    // iter 0: no scale in gemm1; uniform softmax 1/192 applied in redsq.
    gemm1<<<720, 256, 0, stream>>>(Xk, WtT, bij, Pb, it > 0);
    k_redsq<<<dim3(96, 4), 256, 0, stream>>>(
        Pb, out, vT, it == 0 ? (1.0f / 192.0f) : 1.0f, it == 2);
    if (it < 2)
      gemm2_agree<<<720, 256, 0, stream>>>(xT, vT, WtT, bij);
  }
}